// Round 12
// baseline (521.795 us; speedup 1.0000x reference)
//
#include <hip/hip_runtime.h>

// ---------------------------------------------------------------------------
// MultiHeadPooledSelfAttention on gfx950.
// R12 = R11 (BK=64, staging XOR swizzle, single-pass LDS epilogue, XCD head
// grouping for modes 3/4) +
//  * bias folded into the LDS deposit (modes 0/1): readback = pure vector
//    copy, kills ~300 VALU insts/thread of bf2f/f2bf (mode0 was VALU-bound:
//    52% VALUBusy vs 28% MfmaUtil)
//  * softmax gets the SAME head->XCD mapping as modes 3/4 so the S tensor
//    round-trips through one XCD's L2 (mode3 write -> softmax rw -> mode4 rd)
//  * launch merges: cls_all (one kernel), pools as one z=3 dispatch
// ---------------------------------------------------------------------------

typedef unsigned short u16;
typedef __attribute__((ext_vector_type(8))) short short8;   // 8 x bf16
typedef __attribute__((ext_vector_type(4))) float floatx4;
typedef __attribute__((ext_vector_type(4))) unsigned short us4;

__device__ __forceinline__ u16 f2bf(float f) {
  union { float f; unsigned u; } x; x.f = f;
  unsigned r = (x.u + 0x7fffu + ((x.u >> 16) & 1u)) >> 16;
  return (u16)r;
}
__device__ __forceinline__ float bf2f(u16 u) {
  union { unsigned u; float f; } x; x.u = ((unsigned)u) << 16;
  return x.f;
}

__device__ __forceinline__ void gld_lds16(const void* g, void* l) {
  __builtin_amdgcn_global_load_lds(
      (const __attribute__((address_space(1))) void*)g,
      (__attribute__((address_space(3))) void*)l, 16, 0, 0);
}

// ---------------------------------------------------------------------------
struct CvtArgs { const float* src[8]; u16* dst[8]; int n4[8]; };

__global__ __launch_bounds__(256) void cvt_all(CvtArgs a, int total4) {
  int t = blockIdx.x * 256 + threadIdx.x;
  if (t >= total4) return;
#pragma unroll
  for (int s = 0; s < 8; ++s) {
    if (t < a.n4[s]) {
      const float* sp = a.src[s] + (long)t * 4;
      u16* dp = a.dst[s] + (long)t * 4;
      float4 v = *(const float4*)sp;
      dp[0] = f2bf(v.x); dp[1] = f2bf(v.y); dp[2] = f2bf(v.z); dp[3] = f2bf(v.w);
      return;
    }
    t -= a.n4[s];
  }
}

// ---------------------------------------------------------------------------
__global__ __launch_bounds__(256) void emb_kernel(float* __restrict__ e) {
  int t = blockIdx.x * 256 + threadIdx.x;    // < 1024*512
  int c = t & 511, sp = t >> 9;
  int y = sp >> 5, xg = sp & 31;
  int j = c & 127, seg = c >> 7;
  float omega = expf(-(float)j * (9.210340371976184f / 128.f));  // 10000^{-j/128}
  float arg = (float)((seg < 2) ? y : xg) * omega;
  e[t] = (seg & 1) ? cosf(arg) : sinf(arg);
}

// ---------------------------------------------------------------------------
// cls passthrough for PQ/PK/PVt in one kernel.
// ---------------------------------------------------------------------------
__global__ __launch_bounds__(256) void cls_all(
    const u16* __restrict__ Q, const u16* __restrict__ K, const u16* __restrict__ V,
    u16* __restrict__ PQ, u16* __restrict__ PK, u16* __restrict__ PVt) {
  int t = blockIdx.x * 256 + threadIdx.x;    // < 32*512
  int bn = t >> 9, c = t & 511;
  long o = (long)bn * 1025 * 512 + c;
  PQ[o] = Q[o];
  PK[o] = K[o];
  PVt[((long)bn * 512 + c) * 1088] = V[o];
}

// ---------------------------------------------------------------------------
// Softmax: one block per row; XCD head-grouped (head = flat&7 + 8*(s/1025),
// matching modes 3/4) so S stays in the producing XCD's L2.
// Row stride 1088, valid 1025; zero-fills pad.
// ---------------------------------------------------------------------------
__global__ __launch_bounds__(256) void softmax_rows(u16* __restrict__ S) {
  const int t = threadIdx.x;
  int flat = blockIdx.x;
  int xcd = flat & 7, s0 = flat >> 3;
  int zi = s0 / 1025, row_i = s0 - zi * 1025;
  u16* row = S + ((long)(xcd + 8 * zi) * 1025 + row_i) * 1088;
  us4 p = *(const us4*)(row + t * 4);
  float v[4];
  float mx = -1e30f;
#pragma unroll
  for (int i = 0; i < 4; ++i) { v[i] = bf2f(p[i]); mx = fmaxf(mx, v[i]); }
  float e1024 = (t == 0) ? bf2f(row[1024]) : -1e30f;
  mx = fmaxf(mx, e1024);
  __shared__ float red[4], red2[4];
  for (int o = 32; o > 0; o >>= 1) mx = fmaxf(mx, __shfl_xor(mx, o, 64));
  if ((t & 63) == 0) red[t >> 6] = mx;
  __syncthreads();
  mx = fmaxf(fmaxf(red[0], red[1]), fmaxf(red[2], red[3]));
  float s = 0.f;
#pragma unroll
  for (int i = 0; i < 4; ++i) { v[i] = __expf(v[i] - mx); s += v[i]; }
  e1024 = (t == 0) ? __expf(e1024 - mx) : 0.f;
  s += e1024;
  for (int o = 32; o > 0; o >>= 1) s += __shfl_xor(s, o, 64);
  if ((t & 63) == 0) red2[t >> 6] = s;
  __syncthreads();
  s = red2[0] + red2[1] + red2[2] + red2[3];
  float inv = 1.0f / s;
#pragma unroll
  for (int i = 0; i < 4; ++i) p[i] = f2bf(v[i] * inv);
  *(us4*)(row + t * 4) = p;
  if (t < 16) {
    us4 q;
#pragma unroll
    for (int i = 0; i < 4; ++i) q[i] = 0;
    if (t == 0) q[0] = f2bf(e1024 * inv);
    *(us4*)(row + 1024 + t * 4) = q;
  }
}

// ---------------------------------------------------------------------------
__global__ __launch_bounds__(256) void reduce4(const float* __restrict__ part,
                                               const float* __restrict__ bd,
                                               float* __restrict__ out) {
  int t = blockIdx.x * 256 + threadIdx.x;    // < 524800
  long i = (long)t * 4;
  const long STR = 4100ll * 512;
  float4 a = *(const float4*)(part + i);
  float4 b = *(const float4*)(part + i + STR);
  float4 c = *(const float4*)(part + i + 2 * STR);
  float4 d = *(const float4*)(part + i + 3 * STR);
  float4 bb = *(const float4*)(bd + (int)(i & 511));
  float4 r;
  r.x = a.x + b.x + c.x + d.x + bb.x;
  r.y = a.y + b.y + c.y + d.y + bb.y;
  r.z = a.z + b.z + c.z + d.z + bb.z;
  r.w = a.w + b.w + c.w + d.w + bb.w;
  *(float4*)(out + i) = r;
}

// ---------------------------------------------------------------------------
// GEMM-BT: C[m][n] = sum_k A[m][k]*B[n][k], bf16, 128x128 tile, BK=64,
// staging XOR swizzle. Modes:
//  0 PROJ : A=xb, B=[Wq|Wk|Wv] -> Q/K/V (+bias at deposit)
//  1 POOL : bz=0: Q*Wpq(+emb at readback); bz=1: K*Wpk; bz=2: V*Wpv
//           (transposed scalar epilogue -> PVt)   [bias at deposit for 0/1]
//  3 S    : A=PQ[gbz], B=PK[gbz] -> S*scale   [XCD head-grouped 1D]
//  4 O    : A=S[z], B=PVt[gbz] -> stacked (+Q resid)  [XCD head-grouped 1D]
//  5 FIN  : A=stk, B=Wd, split-K x4 -> f32 partials (scalar epilogue)
// ---------------------------------------------------------------------------
struct GP {
  const u16* A; const u16* A2; const u16* A3;
  const u16* B; const u16* B2; const u16* B3;
  const float* c0; const float* c1; const float* c2;
  const float* emb; const u16* resid;
  u16* o0; u16* o1; u16* o2;
  float* of; int bz0;
};

template <int MODE>
__global__ __launch_bounds__(256) void gemm_bt(GP g) {
  constexpr int KLEN = (MODE == 5) ? 1024 : ((MODE == 4) ? 1088 : 512);
  constexpr int KITER = KLEN / 64;
  __shared__ u16 smem[16384];          // As | Bs staging; epilogue tile reuse
  u16* As = smem;
  u16* Bs = smem + 8192;
  const int tid = threadIdx.x;
  const int lane = tid & 63;
  const int wv = tid >> 6;
  const int wr = wv >> 1, wc = wv & 1;

  // Block -> (mt, nt, bz). Modes 3/4: 1D launch, XCD-aware head grouping.
  int mt, nt, bz;
  if constexpr (MODE == 3 || MODE == 4) {
    constexpr int PER = (MODE == 3) ? 81 : 36;
    constexpr int NTW = (MODE == 3) ? 9 : 4;
    int flat = blockIdx.x;
    int xcd = flat & 7, s = flat >> 3;
    bz = xcd + 8 * (s / PER);
    int tile = s % PER;
    mt = tile / NTW;
    nt = tile % NTW;
  } else {
    mt = blockIdx.y; nt = blockIdx.x; bz = blockIdx.z;
  }
  const int gbz = g.bz0 + bz;

  const u16* Ap = g.A;
  const u16* Bp = g.B;
  if constexpr (MODE == 1) {
    if (bz == 1) { Ap = g.A2; Bp = g.B2; }
    else if (bz == 2) { Ap = g.A3; Bp = g.B3; }
  }

  int a_row[4], b_row[4], kx[4];
#pragma unroll
  for (int c = 0; c < 4; ++c) {
    int idx = c * 256 + tid;
    int row = idx >> 3;                       // 0..127
    kx[c] = ((idx & 7) ^ (row & 7)) * 8;      // swizzled k-chunk offset (elems)
    {
      int r = mt * 128 + row;
      int off;
      if constexpr (MODE == 0) { r = r < 4099 ? r : 4099; off = r * 512; }
      else if constexpr (MODE == 1) { off = ((r >> 10) * 1025 + 1 + (r & 1023)) * 512; }
      else if constexpr (MODE == 3) { r = r < 1024 ? r : 1024; off = gbz * (1025 * 512) + r * 512; }
      else if constexpr (MODE == 4) { r = r < 1024 ? r : 1024; off = bz * (1025 * 1088) + r * 1088; }
      else { r = r < 4099 ? r : 4099; off = r * 4096; }
      a_row[c] = off;
    }
    {
      int r = nt * 128 + row;
      int off;
      if constexpr (MODE == 3) { r = r < 1024 ? r : 1024; off = gbz * (1025 * 512) + r * 512; }
      else if constexpr (MODE == 4) { off = gbz * (512 * 1088) + r * 1088; }
      else if constexpr (MODE == 5) { off = r * 4096; }
      else { off = r * 512; }
      b_row[c] = off;
    }
  }

  floatx4 acc[4][4];
#pragma unroll
  for (int i = 0; i < 4; ++i)
#pragma unroll
    for (int j = 0; j < 4; ++j) acc[i][j] = floatx4{0.f, 0.f, 0.f, 0.f};

  const int kbase = (MODE == 5) ? bz * 1024 : 0;
  const int l15 = lane & 15;
  const int lq = lane >> 4;
  const int l7 = lane & 7;

  for (int kt = 0; kt < KITER; ++kt) {
    const int k0 = kbase + kt * 64;
#pragma unroll
    for (int c = 0; c < 4; ++c)
      gld_lds16(Ap + a_row[c] + k0 + kx[c], (char*)As + (c * 256 + wv * 64) * 16);
#pragma unroll
    for (int c = 0; c < 4; ++c)
      gld_lds16(Bp + b_row[c] + k0 + kx[c], (char*)Bs + (c * 256 + wv * 64) * 16);
    __syncthreads();
#pragma unroll
    for (int ks = 0; ks < 2; ++ks) {
      const int ch = ((ks * 4 + lq) ^ l7) * 8;
      short8 af[4], bf[4];
#pragma unroll
      for (int i = 0; i < 4; ++i)
        af[i] = *(const short8*)(As + (wr * 64 + i * 16 + l15) * 64 + ch);
#pragma unroll
      for (int j = 0; j < 4; ++j)
        bf[j] = *(const short8*)(Bs + (wc * 64 + j * 16 + l15) * 64 + ch);
#pragma unroll
      for (int i = 0; i < 4; ++i)
#pragma unroll
        for (int j = 0; j < 4; ++j)
          acc[i][j] = __builtin_amdgcn_mfma_f32_16x16x32_bf16(af[i], bf[j], acc[i][j], 0, 0, 0);
    }
    __syncthreads();
  }

  // ---- Epilogue ---- (C/D frag: col = lane&15, row = (lane>>4)*4 + reg)
  const int ccol = lane & 15;
  const int rgrp = lane >> 4;

  bool use_lds = (MODE != 5);
  if constexpr (MODE == 1) use_lds = (bz != 2);

  if (use_lds) {
    // Per-lane bias (modes 0/1), folded into deposit: 4 scalar loads, x16 reuse.
    float bb[4] = {0.f, 0.f, 0.f, 0.f};
    if constexpr (MODE == 0) {
      int sec = nt >> 5;
      const float* bs = (sec == 0) ? g.c0 : (sec == 1) ? g.c1 : g.c2;
#pragma unroll
      for (int j = 0; j < 4; ++j) bb[j] = bs[(nt & 31) * 128 + wc * 64 + j * 16 + ccol];
    }
    if constexpr (MODE == 1) {
      const float* bs = bz ? g.c1 : g.c0;
#pragma unroll
      for (int j = 0; j < 4; ++j) bb[j] = bs[nt * 128 + wc * 64 + j * 16 + ccol];
    }
#pragma unroll
    for (int i = 0; i < 4; ++i)
#pragma unroll
      for (int j = 0; j < 4; ++j)
#pragma unroll
        for (int rr = 0; rr < 4; ++rr) {
          int lr = wr * 64 + i * 16 + rgrp * 4 + rr;
          int lc = wc * 64 + j * 16 + ccol;
          float v = acc[i][j][rr];
          if constexpr (MODE == 3) v *= 0.04419417382415922f;
          else v += bb[j];
          smem[lr * 128 + (lc ^ (rgrp << 4))] = f2bf(v);
        }
    __syncthreads();
#pragma unroll
    for (int q = 0; q < 8; ++q) {
      int cid = q * 256 + tid;
      int r = cid >> 4;                 // 0..127
      int c = cid & 15;                 // chunk
      int pc = c ^ ((((unsigned)r >> 2) & 3) << 1);
      short8 val = *(const short8*)(smem + r * 128 + pc * 8);
      int grow = mt * 128 + r;
      if constexpr (MODE == 0) {
        if (grow < 4100) {
          int sec = nt >> 5;                     // block-uniform
          int col = (nt & 31) * 128 + c * 8;     // 0..4095
          u16* ob = (sec == 0) ? g.o0 : (sec == 1) ? g.o1 : g.o2;
          int b = grow / 1025, l = grow - b * 1025;
          int n = col >> 9, ch2 = col & 511;
          *(short8*)(ob + ((long)(b * 8 + n) * 1025 + l) * 512 + ch2) = val;
        }
      } else if constexpr (MODE == 1) {
        int bn = grow >> 10, sp = grow & 1023;
        int gcol = nt * 128 + c * 8;             // 0..511
        short8 outv = val;
        if (bz == 0) {
          const float* ep = g.emb + sp * 512 + gcol;
          float4 e0 = *(const float4*)ep;
          float4 e1 = *(const float4*)(ep + 4);
          float ee[8] = {e0.x, e0.y, e0.z, e0.w, e1.x, e1.y, e1.z, e1.w};
#pragma unroll
          for (int e = 0; e < 8; ++e) outv[e] = (short)f2bf(bf2f((u16)val[e]) + ee[e]);
        }
        u16* dst = (bz == 0) ? g.o0 : g.o1;
        *(short8*)(dst + ((long)bn * 1025 + 1 + sp) * 512 + gcol) = outv;
      } else if constexpr (MODE == 3) {
        if (grow <= 1024) {
          int gcol0 = nt * 128 + c * 8;
          u16* dst = g.o0 + ((long)bz * 1025 + grow) * 1088 + gcol0;
          if (gcol0 + 7 <= 1024) *(short8*)dst = val;
          else if (gcol0 <= 1024) dst[0] = (u16)val[0];
        }
      } else {  // MODE 4
        if (grow <= 1024) {
          int gcol0 = nt * 128 + c * 8;          // 0..511
          short8 outv = val;
          if (grow >= 1) {
            short8 rs = *(const short8*)(g.resid + ((long)gbz * 1025 + grow) * 512 + gcol0);
#pragma unroll
            for (int e = 0; e < 8; ++e)
              outv[e] = (short)f2bf(bf2f((u16)val[e]) + bf2f((u16)rs[e]));
          }
          int b = gbz >> 3, n = gbz & 7;
          *(short8*)(g.o0 + (((long)b * 1025 + grow) * 8 + n) * 512 + gcol0) = outv;
        }
      }
    }
  }
  if constexpr (MODE == 1 || MODE == 5) {
    if (!use_lds) {
      // Scalar epilogue: mode1/bz==2 (transposed PVt pool) and mode 5.
#pragma unroll
      for (int i = 0; i < 4; ++i) {
#pragma unroll
        for (int j = 0; j < 4; ++j) {
          const int gcol = nt * 128 + wc * 64 + j * 16 + ccol;
#pragma unroll
          for (int rr = 0; rr < 4; ++rr) {
            const int grow = mt * 128 + wr * 64 + i * 16 + rgrp * 4 + rr;
            float v = acc[i][j][rr];
            if constexpr (MODE == 1) {
              int bn = grow >> 10, sp = grow & 1023;
              v += g.c2[gcol];
              g.o2[((long)bn * 512 + gcol) * 1088 + 1 + sp] = f2bf(v);
            } else {
              if (grow < 4100)
                g.of[((long)bz * 4100 + grow) * 512 + gcol] = v;   // partial
            }
          }
        }
      }
    }
  }
}

// ---------------------------------------------------------------------------
extern "C" void kernel_launch(void* const* d_in, const int* in_sizes, int n_in,
                              void* d_out, int out_size, void* d_ws, size_t ws_size,
                              hipStream_t stream) {
  const float* x   = (const float*)d_in[0];
  const float* Wq  = (const float*)d_in[1];
  const float* bq  = (const float*)d_in[2];
  const float* Wk  = (const float*)d_in[3];
  const float* bk  = (const float*)d_in[4];
  const float* Wv  = (const float*)d_in[5];
  const float* bv  = (const float*)d_in[6];
  const float* Wpq = (const float*)d_in[7];
  const float* bpq = (const float*)d_in[8];
  const float* Wpk = (const float*)d_in[9];
  const float* bpk = (const float*)d_in[10];
  const float* Wpv = (const float*)d_in[11];
  const float* bpv = (const float*)d_in[12];
  const float* Wd  = (const float*)d_in[13];
  const float* bd  = (const float*)d_in[14];
  float* out = (float*)d_out;

  char* ws = (char*)d_ws;
  size_t off = 0;
  auto alloc = [&](size_t bytes) {
    char* p = ws + off;
    off += (bytes + 255) & ~(size_t)255;
    return p;
  };
  // Persistent through attention:
  u16* Wpqb = (u16*)alloc(512ull * 512 * 2);
  u16* Wpkb = (u16*)alloc(512ull * 512 * 2);
  u16* Wpvb = (u16*)alloc(512ull * 512 * 2);
  u16* Wdb  = (u16*)alloc(4096ull * 512 * 2);
  u16* Q    = (u16*)alloc(32ull * 1025 * 512 * 2);
  u16* PQ   = (u16*)alloc(32ull * 1025 * 512 * 2);   // later: f32 partials
  u16* PK   = (u16*)alloc(32ull * 1025 * 512 * 2);   // later: stk (nchunk=1)
  u16* PVt  = (u16*)alloc(32ull * 512 * 1088 * 2);
  // Dead-by-attention group (S aliases from here):
  size_t s_off = off;
  u16* K    = (u16*)alloc(32ull * 1025 * 512 * 2);
  u16* V    = (u16*)alloc(32ull * 1025 * 512 * 2);
  u16* xb   = (u16*)alloc(4100ull * 512 * 2);
  u16* Wqb  = (u16*)alloc(4096ull * 512 * 2);   // Wqb|Wkb|Wvb contiguous
  u16* Wkb  = (u16*)alloc(4096ull * 512 * 2);
  u16* Wvb  = (u16*)alloc(4096ull * 512 * 2);
  float* embp = (float*)alloc(1024ull * 512 * 4);
  size_t fixed_need = off;
  u16* S = (u16*)(ws + s_off);
  float* part = (float*)PQ;   // PQ dead before partials written
  (void)in_sizes; (void)n_in; (void)out_size;

  const size_t sbytes = 1025ull * 1088 * 2;
  size_t need1 = s_off + 32ull * sbytes;
  size_t need2 = s_off + 16ull * sbytes;
  size_t stk4_off = s_off + ((8ull * sbytes + 255) & ~(size_t)255);
  size_t need4 = stk4_off + 4100ull * 4096 * 2;
  int nchunk;
  u16* stk;
  if (ws_size >= need1)      { nchunk = 1; stk = PK; }   // PK dead after mode 3
  else if (ws_size >= need2 && ws_size >= fixed_need) { nchunk = 2; stk = PK; }
  else if (ws_size >= need4 && ws_size >= fixed_need) {
    nchunk = 4; stk = (u16*)(ws + stk4_off);
  } else return;  // clean fail instead of GPU fault
  if (nchunk == 2) {
    size_t stk2_off = s_off + ((16ull * sbytes + 255) & ~(size_t)255);
    if (ws_size >= stk2_off + 4100ull * 4096 * 2) stk = (u16*)(ws + stk2_off);
    else {
      nchunk = 4;
      if (ws_size >= need4) stk = (u16*)(ws + stk4_off);
      else return;
    }
  }
  int hpc = 32 / nchunk;

  // 1) dtype conversions
  CvtArgs ca;
  ca.src[0] = x;   ca.dst[0] = xb;   ca.n4[0] = 4100 * 512 / 4;
  ca.src[1] = Wq;  ca.dst[1] = Wqb;  ca.n4[1] = 4096 * 512 / 4;
  ca.src[2] = Wk;  ca.dst[2] = Wkb;  ca.n4[2] = 4096 * 512 / 4;
  ca.src[3] = Wv;  ca.dst[3] = Wvb;  ca.n4[3] = 4096 * 512 / 4;
  ca.src[4] = Wpq; ca.dst[4] = Wpqb; ca.n4[4] = 512 * 512 / 4;
  ca.src[5] = Wpk; ca.dst[5] = Wpkb; ca.n4[5] = 512 * 512 / 4;
  ca.src[6] = Wpv; ca.dst[6] = Wpvb; ca.n4[6] = 512 * 512 / 4;
  ca.src[7] = Wd;  ca.dst[7] = Wdb;  ca.n4[7] = 512 * 4096 / 4;
  int total4 = 0;
  for (int s = 0; s < 8; ++s) total4 += ca.n4[s];
  cvt_all<<<(total4 + 255) / 256, 256, 0, stream>>>(ca, total4);

  // 2) positional embedding
  emb_kernel<<<(1024 * 512) / 256, 256, 0, stream>>>(embp);

  // 3) merged Q+K+V projection (B = [Wq|Wk|Wv], N=12288), one dispatch
  {
    GP g = {};
    g.A = xb; g.B = Wqb;
    g.c0 = bq; g.c1 = bk; g.c2 = bv;
    g.o0 = Q; g.o1 = K; g.o2 = V;
    gemm_bt<0><<<dim3(96, 33, 1), 256, 0, stream>>>(g);
  }

  // 4) cls passthrough (one kernel)
  cls_all<<<(32 * 512) / 256, 256, 0, stream>>>(Q, K, V, PQ, PK, PVt);

  // 5) pools: Q(+emb), K, V-transposed in ONE z=3 dispatch
  {
    GP g = {};
    g.A = Q; g.A2 = K; g.A3 = V;
    g.B = Wpqb; g.B2 = Wpkb; g.B3 = Wpvb;
    g.c0 = bpq; g.c1 = bpk; g.c2 = bpv; g.emb = embp;
    g.o0 = PQ; g.o1 = PK; g.o2 = PVt;
    gemm_bt<1><<<dim3(4, 256, 3), 256, 0, stream>>>(g);
  }
  // K, V, xb, Wqkv, embp now dead -> S aliases them.

  // 6) attention: logits -> softmax -> O (+Q resid). All XCD head-grouped.
  for (int c = 0; c < nchunk; ++c) {
    GP g3 = {}; g3.A = PQ; g3.B = PK; g3.o0 = S; g3.bz0 = c * hpc;
    gemm_bt<3><<<dim3(81 * hpc, 1, 1), 256, 0, stream>>>(g3);
    softmax_rows<<<hpc * 1025, 256, 0, stream>>>(S);
    GP g4 = {}; g4.A = S; g4.B = PVt; g4.resid = Q; g4.o0 = stk; g4.bz0 = c * hpc;
    gemm_bt<4><<<dim3(36 * hpc, 1, 1), 256, 0, stream>>>(g4);
  }
  // PQ dead -> f32 partials alias it.

  // 7) final projection, split-K x4 -> partials, then reduce (+bias)
  {
    GP g = {}; g.A = stk; g.B = Wdb; g.of = part;
    gemm_bt<5><<<dim3(4, 33, 4), 256, 0, stream>>>(g);
  }
  reduce4<<<(4100 * 512 / 4 + 255) / 256, 256, 0, stream>>>(part, bd, out);
}

// Round 13
// 503.912 us; speedup vs baseline: 1.0355x; 1.0355x over previous
//
#include <hip/hip_runtime.h>

// ---------------------------------------------------------------------------
// MultiHeadPooledSelfAttention on gfx950.
// R13 = R12 minus the z=3 pool merge (it fused the scalar PVt epilogue into
// mode1 -> VGPR 80->120, occ 27->20%, pools 95->120us = the whole R12
// regression). Pools split again (mode1 Q/K LDS-ep, mode2 V scalar-ep), and
// BOTH now use the validated XCD head/slice grouping (flat&7) so each XCD
// reads a contiguous 4MB A-slice once instead of 4x cross-XCD refetch
// (pool FETCH was 202MB vs ~103 ideal). Keeps: BK=64 + staging XOR swizzle,
// single-pass LDS epilogue w/ bias-at-deposit, cls_all, XCD-grouped softmax
// and modes 3/4, split-K x4 final.
// ---------------------------------------------------------------------------

typedef unsigned short u16;
typedef __attribute__((ext_vector_type(8))) short short8;   // 8 x bf16
typedef __attribute__((ext_vector_type(4))) float floatx4;
typedef __attribute__((ext_vector_type(4))) unsigned short us4;

__device__ __forceinline__ u16 f2bf(float f) {
  union { float f; unsigned u; } x; x.f = f;
  unsigned r = (x.u + 0x7fffu + ((x.u >> 16) & 1u)) >> 16;
  return (u16)r;
}
__device__ __forceinline__ float bf2f(u16 u) {
  union { unsigned u; float f; } x; x.u = ((unsigned)u) << 16;
  return x.f;
}

__device__ __forceinline__ void gld_lds16(const void* g, void* l) {
  __builtin_amdgcn_global_load_lds(
      (const __attribute__((address_space(1))) void*)g,
      (__attribute__((address_space(3))) void*)l, 16, 0, 0);
}

// ---------------------------------------------------------------------------
struct CvtArgs { const float* src[8]; u16* dst[8]; int n4[8]; };

__global__ __launch_bounds__(256) void cvt_all(CvtArgs a, int total4) {
  int t = blockIdx.x * 256 + threadIdx.x;
  if (t >= total4) return;
#pragma unroll
  for (int s = 0; s < 8; ++s) {
    if (t < a.n4[s]) {
      const float* sp = a.src[s] + (long)t * 4;
      u16* dp = a.dst[s] + (long)t * 4;
      float4 v = *(const float4*)sp;
      dp[0] = f2bf(v.x); dp[1] = f2bf(v.y); dp[2] = f2bf(v.z); dp[3] = f2bf(v.w);
      return;
    }
    t -= a.n4[s];
  }
}

// ---------------------------------------------------------------------------
__global__ __launch_bounds__(256) void emb_kernel(float* __restrict__ e) {
  int t = blockIdx.x * 256 + threadIdx.x;    // < 1024*512
  int c = t & 511, sp = t >> 9;
  int y = sp >> 5, xg = sp & 31;
  int j = c & 127, seg = c >> 7;
  float omega = expf(-(float)j * (9.210340371976184f / 128.f));  // 10000^{-j/128}
  float arg = (float)((seg < 2) ? y : xg) * omega;
  e[t] = (seg & 1) ? cosf(arg) : sinf(arg);
}

// ---------------------------------------------------------------------------
__global__ __launch_bounds__(256) void cls_all(
    const u16* __restrict__ Q, const u16* __restrict__ K, const u16* __restrict__ V,
    u16* __restrict__ PQ, u16* __restrict__ PK, u16* __restrict__ PVt) {
  int t = blockIdx.x * 256 + threadIdx.x;    // < 32*512
  int bn = t >> 9, c = t & 511;
  long o = (long)bn * 1025 * 512 + c;
  PQ[o] = Q[o];
  PK[o] = K[o];
  PVt[((long)bn * 512 + c) * 1088] = V[o];
}

// ---------------------------------------------------------------------------
// Softmax: one block per row; XCD head-grouped (matches modes 3/4).
// ---------------------------------------------------------------------------
__global__ __launch_bounds__(256) void softmax_rows(u16* __restrict__ S) {
  const int t = threadIdx.x;
  int flat = blockIdx.x;
  int xcd = flat & 7, s0 = flat >> 3;
  int zi = s0 / 1025, row_i = s0 - zi * 1025;
  u16* row = S + ((long)(xcd + 8 * zi) * 1025 + row_i) * 1088;
  us4 p = *(const us4*)(row + t * 4);
  float v[4];
  float mx = -1e30f;
#pragma unroll
  for (int i = 0; i < 4; ++i) { v[i] = bf2f(p[i]); mx = fmaxf(mx, v[i]); }
  float e1024 = (t == 0) ? bf2f(row[1024]) : -1e30f;
  mx = fmaxf(mx, e1024);
  __shared__ float red[4], red2[4];
  for (int o = 32; o > 0; o >>= 1) mx = fmaxf(mx, __shfl_xor(mx, o, 64));
  if ((t & 63) == 0) red[t >> 6] = mx;
  __syncthreads();
  mx = fmaxf(fmaxf(red[0], red[1]), fmaxf(red[2], red[3]));
  float s = 0.f;
#pragma unroll
  for (int i = 0; i < 4; ++i) { v[i] = __expf(v[i] - mx); s += v[i]; }
  e1024 = (t == 0) ? __expf(e1024 - mx) : 0.f;
  s += e1024;
  for (int o = 32; o > 0; o >>= 1) s += __shfl_xor(s, o, 64);
  if ((t & 63) == 0) red2[t >> 6] = s;
  __syncthreads();
  s = red2[0] + red2[1] + red2[2] + red2[3];
  float inv = 1.0f / s;
#pragma unroll
  for (int i = 0; i < 4; ++i) p[i] = f2bf(v[i] * inv);
  *(us4*)(row + t * 4) = p;
  if (t < 16) {
    us4 q;
#pragma unroll
    for (int i = 0; i < 4; ++i) q[i] = 0;
    if (t == 0) q[0] = f2bf(e1024 * inv);
    *(us4*)(row + 1024 + t * 4) = q;
  }
}

// ---------------------------------------------------------------------------
__global__ __launch_bounds__(256) void reduce4(const float* __restrict__ part,
                                               const float* __restrict__ bd,
                                               float* __restrict__ out) {
  int t = blockIdx.x * 256 + threadIdx.x;    // < 524800
  long i = (long)t * 4;
  const long STR = 4100ll * 512;
  float4 a = *(const float4*)(part + i);
  float4 b = *(const float4*)(part + i + STR);
  float4 c = *(const float4*)(part + i + 2 * STR);
  float4 d = *(const float4*)(part + i + 3 * STR);
  float4 bb = *(const float4*)(bd + (int)(i & 511));
  float4 r;
  r.x = a.x + b.x + c.x + d.x + bb.x;
  r.y = a.y + b.y + c.y + d.y + bb.y;
  r.z = a.z + b.z + c.z + d.z + bb.z;
  r.w = a.w + b.w + c.w + d.w + bb.w;
  *(float4*)(out + i) = r;
}

// ---------------------------------------------------------------------------
// GEMM-BT: C[m][n] = sum_k A[m][k]*B[n][k], bf16, 128x128 tile, BK=64,
// staging XOR swizzle. Modes:
//  0 PROJ : A=xb, B=[Wq|Wk|Wv] -> Q/K/V (bias at deposit), grid (96,33)
//  1 POOL : 1D XCD-grouped; bz=0: Q*Wpq (+emb at readback), bz=1: K*Wpk
//  2 POOLT: 1D XCD-grouped; V*Wpv -> PVt transposed (scalar epilogue)
//  3 S    : 1D XCD head-grouped; PQ*PK^T -> S*scale
//  4 O    : 1D XCD head-grouped; S*PVt^T -> stacked (+Q resid)
//  5 FIN  : A=stk, B=Wd, split-K x4 -> f32 partials (scalar epilogue)
// ---------------------------------------------------------------------------
struct GP {
  const u16* A; const u16* A2; const u16* B; const u16* B2;
  const float* c0; const float* c1; const float* c2;
  const float* emb; const u16* resid;
  u16* o0; u16* o1; u16* o2;
  float* of; int bz0;
};

template <int MODE>
__global__ __launch_bounds__(256) void gemm_bt(GP g) {
  constexpr int KLEN = (MODE == 5) ? 1024 : ((MODE == 4) ? 1088 : 512);
  constexpr int KITER = KLEN / 64;
  constexpr bool LDSEP = (MODE == 0 || MODE == 1 || MODE == 3 || MODE == 4);
  __shared__ u16 smem[16384];          // As | Bs staging; epilogue tile reuse
  u16* As = smem;
  u16* Bs = smem + 8192;
  const int tid = threadIdx.x;
  const int lane = tid & 63;
  const int wv = tid >> 6;
  const int wr = wv >> 1, wc = wv & 1;

  // Block -> (mt, nt, bz). XCD grouping (flat&7) for modes 1/2/3/4.
  int mt, nt, bz;
  if constexpr (MODE == 3 || MODE == 4) {
    constexpr int PER = (MODE == 3) ? 81 : 36;
    constexpr int NTW = (MODE == 3) ? 9 : 4;
    int flat = blockIdx.x;
    int xcd = flat & 7, s = flat >> 3;
    bz = xcd + 8 * (s / PER);
    int tile = s % PER;
    mt = tile / NTW;
    nt = tile % NTW;
  } else if constexpr (MODE == 1) {
    int flat = blockIdx.x;               // 2048 blocks
    int xcd = flat & 7, s = flat >> 3;   // s: 0..255
    bz = s >> 7;                         // 0 = Q-pool, 1 = K-pool
    int rem = s & 127;
    mt = xcd * 32 + (rem >> 2);          // contiguous 32-mt slice per XCD
    nt = rem & 3;
  } else if constexpr (MODE == 2) {
    int flat = blockIdx.x;               // 1024 blocks
    int xcd = flat & 7, s = flat >> 3;   // s: 0..127
    bz = 0;
    mt = xcd * 32 + (s >> 2);
    nt = s & 3;
  } else {
    mt = blockIdx.y; nt = blockIdx.x; bz = blockIdx.z;
  }
  const int gbz = g.bz0 + bz;

  const u16* Ap = g.A;
  const u16* Bp = g.B;
  if constexpr (MODE == 1) {
    if (bz == 1) { Ap = g.A2; Bp = g.B2; }
  }

  int a_row[4], b_row[4], kx[4];
#pragma unroll
  for (int c = 0; c < 4; ++c) {
    int idx = c * 256 + tid;
    int row = idx >> 3;                       // 0..127
    kx[c] = ((idx & 7) ^ (row & 7)) * 8;      // swizzled k-chunk offset (elems)
    {
      int r = mt * 128 + row;
      int off;
      if constexpr (MODE == 0) { r = r < 4099 ? r : 4099; off = r * 512; }
      else if constexpr (MODE == 1 || MODE == 2) { off = ((r >> 10) * 1025 + 1 + (r & 1023)) * 512; }
      else if constexpr (MODE == 3) { r = r < 1024 ? r : 1024; off = gbz * (1025 * 512) + r * 512; }
      else if constexpr (MODE == 4) { r = r < 1024 ? r : 1024; off = bz * (1025 * 1088) + r * 1088; }
      else { r = r < 4099 ? r : 4099; off = r * 4096; }
      a_row[c] = off;
    }
    {
      int r = nt * 128 + row;
      int off;
      if constexpr (MODE == 3) { r = r < 1024 ? r : 1024; off = gbz * (1025 * 512) + r * 512; }
      else if constexpr (MODE == 4) { off = gbz * (512 * 1088) + r * 1088; }
      else if constexpr (MODE == 5) { off = r * 4096; }
      else { off = r * 512; }
      b_row[c] = off;
    }
  }

  floatx4 acc[4][4];
#pragma unroll
  for (int i = 0; i < 4; ++i)
#pragma unroll
    for (int j = 0; j < 4; ++j) acc[i][j] = floatx4{0.f, 0.f, 0.f, 0.f};

  const int kbase = (MODE == 5) ? bz * 1024 : 0;
  const int l15 = lane & 15;
  const int lq = lane >> 4;
  const int l7 = lane & 7;

  for (int kt = 0; kt < KITER; ++kt) {
    const int k0 = kbase + kt * 64;
#pragma unroll
    for (int c = 0; c < 4; ++c)
      gld_lds16(Ap + a_row[c] + k0 + kx[c], (char*)As + (c * 256 + wv * 64) * 16);
#pragma unroll
    for (int c = 0; c < 4; ++c)
      gld_lds16(Bp + b_row[c] + k0 + kx[c], (char*)Bs + (c * 256 + wv * 64) * 16);
    __syncthreads();
#pragma unroll
    for (int ks = 0; ks < 2; ++ks) {
      const int ch = ((ks * 4 + lq) ^ l7) * 8;
      short8 af[4], bf[4];
#pragma unroll
      for (int i = 0; i < 4; ++i)
        af[i] = *(const short8*)(As + (wr * 64 + i * 16 + l15) * 64 + ch);
#pragma unroll
      for (int j = 0; j < 4; ++j)
        bf[j] = *(const short8*)(Bs + (wc * 64 + j * 16 + l15) * 64 + ch);
#pragma unroll
      for (int i = 0; i < 4; ++i)
#pragma unroll
        for (int j = 0; j < 4; ++j)
          acc[i][j] = __builtin_amdgcn_mfma_f32_16x16x32_bf16(af[i], bf[j], acc[i][j], 0, 0, 0);
    }
    __syncthreads();
  }

  // ---- Epilogue ---- (C/D frag: col = lane&15, row = (lane>>4)*4 + reg)
  const int ccol = lane & 15;
  const int rgrp = lane >> 4;

  if constexpr (LDSEP) {
    // Per-lane bias (modes 0/1), folded into deposit: 4 scalar loads, x16 reuse.
    float bb[4] = {0.f, 0.f, 0.f, 0.f};
    if constexpr (MODE == 0) {
      int sec = nt >> 5;
      const float* bs = (sec == 0) ? g.c0 : (sec == 1) ? g.c1 : g.c2;
#pragma unroll
      for (int j = 0; j < 4; ++j) bb[j] = bs[(nt & 31) * 128 + wc * 64 + j * 16 + ccol];
    }
    if constexpr (MODE == 1) {
      const float* bs = bz ? g.c1 : g.c0;
#pragma unroll
      for (int j = 0; j < 4; ++j) bb[j] = bs[nt * 128 + wc * 64 + j * 16 + ccol];
    }
#pragma unroll
    for (int i = 0; i < 4; ++i)
#pragma unroll
      for (int j = 0; j < 4; ++j)
#pragma unroll
        for (int rr = 0; rr < 4; ++rr) {
          int lr = wr * 64 + i * 16 + rgrp * 4 + rr;
          int lc = wc * 64 + j * 16 + ccol;
          float v = acc[i][j][rr];
          if constexpr (MODE == 3) v *= 0.04419417382415922f;
          else v += bb[j];
          smem[lr * 128 + (lc ^ (rgrp << 4))] = f2bf(v);
        }
    __syncthreads();
#pragma unroll
    for (int q = 0; q < 8; ++q) {
      int cid = q * 256 + tid;
      int r = cid >> 4;                 // 0..127
      int c = cid & 15;                 // chunk
      int pc = c ^ ((((unsigned)r >> 2) & 3) << 1);
      short8 val = *(const short8*)(smem + r * 128 + pc * 8);
      int grow = mt * 128 + r;
      if constexpr (MODE == 0) {
        if (grow < 4100) {
          int sec = nt >> 5;                     // block-uniform
          int col = (nt & 31) * 128 + c * 8;     // 0..4095
          u16* ob = (sec == 0) ? g.o0 : (sec == 1) ? g.o1 : g.o2;
          int b = grow / 1025, l = grow - b * 1025;
          int n = col >> 9, ch2 = col & 511;
          *(short8*)(ob + ((long)(b * 8 + n) * 1025 + l) * 512 + ch2) = val;
        }
      } else if constexpr (MODE == 1) {
        int bn = grow >> 10, sp = grow & 1023;
        int gcol = nt * 128 + c * 8;             // 0..511
        short8 outv = val;
        if (bz == 0) {
          const float* ep = g.emb + sp * 512 + gcol;
          float4 e0 = *(const float4*)ep;
          float4 e1 = *(const float4*)(ep + 4);
          float ee[8] = {e0.x, e0.y, e0.z, e0.w, e1.x, e1.y, e1.z, e1.w};
#pragma unroll
          for (int e = 0; e < 8; ++e) outv[e] = (short)f2bf(bf2f((u16)val[e]) + ee[e]);
        }
        u16* dst = (bz == 0) ? g.o0 : g.o1;
        *(short8*)(dst + ((long)bn * 1025 + 1 + sp) * 512 + gcol) = outv;
      } else if constexpr (MODE == 3) {
        if (grow <= 1024) {
          int gcol0 = nt * 128 + c * 8;
          u16* dst = g.o0 + ((long)bz * 1025 + grow) * 1088 + gcol0;
          if (gcol0 + 7 <= 1024) *(short8*)dst = val;
          else if (gcol0 <= 1024) dst[0] = (u16)val[0];
        }
      } else {  // MODE 4
        if (grow <= 1024) {
          int gcol0 = nt * 128 + c * 8;          // 0..511
          short8 outv = val;
          if (grow >= 1) {
            short8 rs = *(const short8*)(g.resid + ((long)gbz * 1025 + grow) * 512 + gcol0);
#pragma unroll
            for (int e = 0; e < 8; ++e)
              outv[e] = (short)f2bf(bf2f((u16)val[e]) + bf2f((u16)rs[e]));
          }
          int b = gbz >> 3, n = gbz & 7;
          *(short8*)(g.o0 + (((long)b * 1025 + grow) * 8 + n) * 512 + gcol0) = outv;
        }
      }
    }
  } else {
    // Scalar epilogue for modes 2 (transposed PVt pool) and 5 (f32 partials).
#pragma unroll
    for (int i = 0; i < 4; ++i) {
#pragma unroll
      for (int j = 0; j < 4; ++j) {
        const int gcol = nt * 128 + wc * 64 + j * 16 + ccol;
#pragma unroll
        for (int rr = 0; rr < 4; ++rr) {
          const int grow = mt * 128 + wr * 64 + i * 16 + rgrp * 4 + rr;
          float v = acc[i][j][rr];
          if constexpr (MODE == 2) {
            int bn = grow >> 10, sp = grow & 1023;
            v += g.c0[gcol];
            g.o0[((long)bn * 512 + gcol) * 1088 + 1 + sp] = f2bf(v);
          } else {
            if (grow < 4100)
              g.of[((long)bz * 4100 + grow) * 512 + gcol] = v;   // partial
          }
        }
      }
    }
  }
}

// ---------------------------------------------------------------------------
extern "C" void kernel_launch(void* const* d_in, const int* in_sizes, int n_in,
                              void* d_out, int out_size, void* d_ws, size_t ws_size,
                              hipStream_t stream) {
  const float* x   = (const float*)d_in[0];
  const float* Wq  = (const float*)d_in[1];
  const float* bq  = (const float*)d_in[2];
  const float* Wk  = (const float*)d_in[3];
  const float* bk  = (const float*)d_in[4];
  const float* Wv  = (const float*)d_in[5];
  const float* bv  = (const float*)d_in[6];
  const float* Wpq = (const float*)d_in[7];
  const float* bpq = (const float*)d_in[8];
  const float* Wpk = (const float*)d_in[9];
  const float* bpk = (const float*)d_in[10];
  const float* Wpv = (const float*)d_in[11];
  const float* bpv = (const float*)d_in[12];
  const float* Wd  = (const float*)d_in[13];
  const float* bd  = (const float*)d_in[14];
  float* out = (float*)d_out;

  char* ws = (char*)d_ws;
  size_t off = 0;
  auto alloc = [&](size_t bytes) {
    char* p = ws + off;
    off += (bytes + 255) & ~(size_t)255;
    return p;
  };
  // Persistent through attention:
  u16* Wpqb = (u16*)alloc(512ull * 512 * 2);
  u16* Wpkb = (u16*)alloc(512ull * 512 * 2);
  u16* Wpvb = (u16*)alloc(512ull * 512 * 2);
  u16* Wdb  = (u16*)alloc(4096ull * 512 * 2);
  u16* Q    = (u16*)alloc(32ull * 1025 * 512 * 2);
  u16* PQ   = (u16*)alloc(32ull * 1025 * 512 * 2);   // later: f32 partials
  u16* PK   = (u16*)alloc(32ull * 1025 * 512 * 2);   // later: stk (nchunk=1)
  u16* PVt  = (u16*)alloc(32ull * 512 * 1088 * 2);
  // Dead-by-attention group (S aliases from here):
  size_t s_off = off;
  u16* K    = (u16*)alloc(32ull * 1025 * 512 * 2);
  u16* V    = (u16*)alloc(32ull * 1025 * 512 * 2);
  u16* xb   = (u16*)alloc(4100ull * 512 * 2);
  u16* Wqb  = (u16*)alloc(4096ull * 512 * 2);   // Wqb|Wkb|Wvb contiguous
  u16* Wkb  = (u16*)alloc(4096ull * 512 * 2);
  u16* Wvb  = (u16*)alloc(4096ull * 512 * 2);
  float* embp = (float*)alloc(1024ull * 512 * 4);
  size_t fixed_need = off;
  u16* S = (u16*)(ws + s_off);
  float* part = (float*)PQ;   // PQ dead before partials written
  (void)in_sizes; (void)n_in; (void)out_size;

  const size_t sbytes = 1025ull * 1088 * 2;
  size_t need1 = s_off + 32ull * sbytes;
  size_t need2 = s_off + 16ull * sbytes;
  size_t stk4_off = s_off + ((8ull * sbytes + 255) & ~(size_t)255);
  size_t need4 = stk4_off + 4100ull * 4096 * 2;
  int nchunk;
  u16* stk;
  if (ws_size >= need1)      { nchunk = 1; stk = PK; }   // PK dead after mode 3
  else if (ws_size >= need2 && ws_size >= fixed_need) { nchunk = 2; stk = PK; }
  else if (ws_size >= need4 && ws_size >= fixed_need) {
    nchunk = 4; stk = (u16*)(ws + stk4_off);
  } else return;  // clean fail instead of GPU fault
  if (nchunk == 2) {
    size_t stk2_off = s_off + ((16ull * sbytes + 255) & ~(size_t)255);
    if (ws_size >= stk2_off + 4100ull * 4096 * 2) stk = (u16*)(ws + stk2_off);
    else {
      nchunk = 4;
      if (ws_size >= need4) stk = (u16*)(ws + stk4_off);
      else return;
    }
  }
  int hpc = 32 / nchunk;

  // 1) dtype conversions
  CvtArgs ca;
  ca.src[0] = x;   ca.dst[0] = xb;   ca.n4[0] = 4100 * 512 / 4;
  ca.src[1] = Wq;  ca.dst[1] = Wqb;  ca.n4[1] = 4096 * 512 / 4;
  ca.src[2] = Wk;  ca.dst[2] = Wkb;  ca.n4[2] = 4096 * 512 / 4;
  ca.src[3] = Wv;  ca.dst[3] = Wvb;  ca.n4[3] = 4096 * 512 / 4;
  ca.src[4] = Wpq; ca.dst[4] = Wpqb; ca.n4[4] = 512 * 512 / 4;
  ca.src[5] = Wpk; ca.dst[5] = Wpkb; ca.n4[5] = 512 * 512 / 4;
  ca.src[6] = Wpv; ca.dst[6] = Wpvb; ca.n4[6] = 512 * 512 / 4;
  ca.src[7] = Wd;  ca.dst[7] = Wdb;  ca.n4[7] = 512 * 4096 / 4;
  int total4 = 0;
  for (int s = 0; s < 8; ++s) total4 += ca.n4[s];
  cvt_all<<<(total4 + 255) / 256, 256, 0, stream>>>(ca, total4);

  // 2) positional embedding
  emb_kernel<<<(1024 * 512) / 256, 256, 0, stream>>>(embp);

  // 3) merged Q+K+V projection (B = [Wq|Wk|Wv], N=12288), one dispatch
  {
    GP g = {};
    g.A = xb; g.B = Wqb;
    g.c0 = bq; g.c1 = bk; g.c2 = bv;
    g.o0 = Q; g.o1 = K; g.o2 = V;
    gemm_bt<0><<<dim3(96, 33, 1), 256, 0, stream>>>(g);
  }

  // 4) cls passthrough (one kernel)
  cls_all<<<(32 * 512) / 256, 256, 0, stream>>>(Q, K, V, PQ, PK, PVt);

  // 5) pools: Q(+emb) and K in one lean mode-1 dispatch; V pool separate
  {
    GP g = {};
    g.A = Q; g.A2 = K; g.B = Wpqb; g.B2 = Wpkb;
    g.c0 = bpq; g.c1 = bpk; g.emb = embp;
    g.o0 = PQ; g.o1 = PK;
    gemm_bt<1><<<dim3(2048, 1, 1), 256, 0, stream>>>(g);
  }
  {
    GP g = {};
    g.A = V; g.B = Wpvb; g.c0 = bpv; g.o0 = PVt;
    gemm_bt<2><<<dim3(1024, 1, 1), 256, 0, stream>>>(g);
  }
  // K, V, xb, Wqkv, embp now dead -> S aliases them.

  // 6) attention: logits -> softmax -> O (+Q resid). All XCD head-grouped.
  for (int c = 0; c < nchunk; ++c) {
    GP g3 = {}; g3.A = PQ; g3.B = PK; g3.o0 = S; g3.bz0 = c * hpc;
    gemm_bt<3><<<dim3(81 * hpc, 1, 1), 256, 0, stream>>>(g3);
    softmax_rows<<<hpc * 1025, 256, 0, stream>>>(S);
    GP g4 = {}; g4.A = S; g4.B = PVt; g4.resid = Q; g4.o0 = stk; g4.bz0 = c * hpc;
    gemm_bt<4><<<dim3(36 * hpc, 1, 1), 256, 0, stream>>>(g4);
  }
  // PQ dead -> f32 partials alias it.

  // 7) final projection, split-K x4 -> partials, then reduce (+bias)
  {
    GP g = {}; g.A = stk; g.B = Wdb; g.of = part;
    gemm_bt<5><<<dim3(4, 33, 4), 256, 0, stream>>>(g);
  }
  reduce4<<<(4100 * 512 / 4 + 255) / 256, 256, 0, stream>>>(part, bd, out);
}

// Round 14
// 463.831 us; speedup vs baseline: 1.1250x; 1.0864x over previous
//
#include <hip/hip_runtime.h>

// ---------------------------------------------------------------------------
// MultiHeadPooledSelfAttention on gfx950.
// R14 = R13 with:
//  * bias folded into ACC INIT (modes 0/1): acc starts at bias, MFMA
//    accumulates on top -> deposit = pure f2bf, readback = pure copy, and
//    bias regs die before the K-loop. Fixes R12/R13's VGPR 80->92 / occ
//    27->18% regression on mode 0 (bias-at-deposit kept bb[] live).
//  * wave-per-row softmax (4 rows/block, 64-lane shuffle-only reduction,
//    no LDS / no __syncthreads), same head->XCD mapping.
// Keeps: BK=64 staging XOR swizzle (0 conflicts), single-pass LDS epilogue,
// XCD grouping for pools/mode3/mode4/softmax, split-K x4 final projection.
// ---------------------------------------------------------------------------

typedef unsigned short u16;
typedef __attribute__((ext_vector_type(8))) short short8;   // 8 x bf16
typedef __attribute__((ext_vector_type(4))) float floatx4;
typedef __attribute__((ext_vector_type(4))) unsigned short us4;

__device__ __forceinline__ u16 f2bf(float f) {
  union { float f; unsigned u; } x; x.f = f;
  unsigned r = (x.u + 0x7fffu + ((x.u >> 16) & 1u)) >> 16;
  return (u16)r;
}
__device__ __forceinline__ float bf2f(u16 u) {
  union { unsigned u; float f; } x; x.u = ((unsigned)u) << 16;
  return x.f;
}

__device__ __forceinline__ void gld_lds16(const void* g, void* l) {
  __builtin_amdgcn_global_load_lds(
      (const __attribute__((address_space(1))) void*)g,
      (__attribute__((address_space(3))) void*)l, 16, 0, 0);
}

// ---------------------------------------------------------------------------
struct CvtArgs { const float* src[8]; u16* dst[8]; int n4[8]; };

__global__ __launch_bounds__(256) void cvt_all(CvtArgs a, int total4) {
  int t = blockIdx.x * 256 + threadIdx.x;
  if (t >= total4) return;
#pragma unroll
  for (int s = 0; s < 8; ++s) {
    if (t < a.n4[s]) {
      const float* sp = a.src[s] + (long)t * 4;
      u16* dp = a.dst[s] + (long)t * 4;
      float4 v = *(const float4*)sp;
      dp[0] = f2bf(v.x); dp[1] = f2bf(v.y); dp[2] = f2bf(v.z); dp[3] = f2bf(v.w);
      return;
    }
    t -= a.n4[s];
  }
}

// ---------------------------------------------------------------------------
__global__ __launch_bounds__(256) void emb_kernel(float* __restrict__ e) {
  int t = blockIdx.x * 256 + threadIdx.x;    // < 1024*512
  int c = t & 511, sp = t >> 9;
  int y = sp >> 5, xg = sp & 31;
  int j = c & 127, seg = c >> 7;
  float omega = expf(-(float)j * (9.210340371976184f / 128.f));  // 10000^{-j/128}
  float arg = (float)((seg < 2) ? y : xg) * omega;
  e[t] = (seg & 1) ? cosf(arg) : sinf(arg);
}

// ---------------------------------------------------------------------------
__global__ __launch_bounds__(256) void cls_all(
    const u16* __restrict__ Q, const u16* __restrict__ K, const u16* __restrict__ V,
    u16* __restrict__ PQ, u16* __restrict__ PK, u16* __restrict__ PVt) {
  int t = blockIdx.x * 256 + threadIdx.x;    // < 32*512
  int bn = t >> 9, c = t & 511;
  long o = (long)bn * 1025 * 512 + c;
  PQ[o] = Q[o];
  PK[o] = K[o];
  PVt[((long)bn * 512 + c) * 1088] = V[o];
}

// ---------------------------------------------------------------------------
// Softmax: one WAVE per row, 4 rows/block. XCD head-grouped (head = flat&7 +
// 8*zi, matching modes 3/4). Row stride 1088, valid 1025; zero-fills pad.
// Grid: 257 * heads / ... = 257*hpc blocks (4 rows each, guard row<=1024).
// ---------------------------------------------------------------------------
__global__ __launch_bounds__(256) void softmax_rows(u16* __restrict__ S) {
  int flat = blockIdx.x;
  int xcd = flat & 7, s0 = flat >> 3;
  int zi = s0 / 257, blk = s0 - zi * 257;
  int head = xcd + 8 * zi;
  int wv = threadIdx.x >> 6, lane = threadIdx.x & 63;
  int row_i = blk * 4 + wv;
  if (row_i > 1024) return;
  u16* row = S + ((long)head * 1025 + row_i) * 1088;
  float v[16];
  float mx = -1e30f;
#pragma unroll
  for (int i = 0; i < 4; ++i) {
    us4 p = *(const us4*)(row + i * 256 + lane * 4);
#pragma unroll
    for (int e = 0; e < 4; ++e) { v[i * 4 + e] = bf2f(p[e]); mx = fmaxf(mx, v[i * 4 + e]); }
  }
  float e1024 = (lane == 0) ? bf2f(row[1024]) : -1e30f;
  mx = fmaxf(mx, e1024);
  for (int o = 32; o > 0; o >>= 1) mx = fmaxf(mx, __shfl_xor(mx, o, 64));
  float s = 0.f;
#pragma unroll
  for (int i = 0; i < 16; ++i) { v[i] = __expf(v[i] - mx); s += v[i]; }
  e1024 = (lane == 0) ? __expf(e1024 - mx) : 0.f;
  s += e1024;
  for (int o = 32; o > 0; o >>= 1) s += __shfl_xor(s, o, 64);
  float inv = 1.0f / s;
#pragma unroll
  for (int i = 0; i < 4; ++i) {
    us4 q;
#pragma unroll
    for (int e = 0; e < 4; ++e) q[e] = f2bf(v[i * 4 + e] * inv);
    *(us4*)(row + i * 256 + lane * 4) = q;
  }
  if (lane < 16) {
    us4 q;
#pragma unroll
    for (int e = 0; e < 4; ++e) q[e] = 0;
    if (lane == 0) q[0] = f2bf(e1024 * inv);
    *(us4*)(row + 1024 + lane * 4) = q;
  }
}

// ---------------------------------------------------------------------------
__global__ __launch_bounds__(256) void reduce4(const float* __restrict__ part,
                                               const float* __restrict__ bd,
                                               float* __restrict__ out) {
  int t = blockIdx.x * 256 + threadIdx.x;    // < 524800
  long i = (long)t * 4;
  const long STR = 4100ll * 512;
  float4 a = *(const float4*)(part + i);
  float4 b = *(const float4*)(part + i + STR);
  float4 c = *(const float4*)(part + i + 2 * STR);
  float4 d = *(const float4*)(part + i + 3 * STR);
  float4 bb = *(const float4*)(bd + (int)(i & 511));
  float4 r;
  r.x = a.x + b.x + c.x + d.x + bb.x;
  r.y = a.y + b.y + c.y + d.y + bb.y;
  r.z = a.z + b.z + c.z + d.z + bb.z;
  r.w = a.w + b.w + c.w + d.w + bb.w;
  *(float4*)(out + i) = r;
}

// ---------------------------------------------------------------------------
// GEMM-BT: C[m][n] = sum_k A[m][k]*B[n][k], bf16, 128x128 tile, BK=64,
// staging XOR swizzle. Modes as R13; bias now enters via acc init.
// ---------------------------------------------------------------------------
struct GP {
  const u16* A; const u16* A2; const u16* B; const u16* B2;
  const float* c0; const float* c1; const float* c2;
  const float* emb; const u16* resid;
  u16* o0; u16* o1; u16* o2;
  float* of; int bz0;
};

template <int MODE>
__global__ __launch_bounds__(256) void gemm_bt(GP g) {
  constexpr int KLEN = (MODE == 5) ? 1024 : ((MODE == 4) ? 1088 : 512);
  constexpr int KITER = KLEN / 64;
  constexpr bool LDSEP = (MODE == 0 || MODE == 1 || MODE == 3 || MODE == 4);
  __shared__ u16 smem[16384];          // As | Bs staging; epilogue tile reuse
  u16* As = smem;
  u16* Bs = smem + 8192;
  const int tid = threadIdx.x;
  const int lane = tid & 63;
  const int wv = tid >> 6;
  const int wr = wv >> 1, wc = wv & 1;
  const int ccol = lane & 15;
  const int rgrp = lane >> 4;

  // Block -> (mt, nt, bz). XCD grouping (flat&7) for modes 1/2/3/4.
  int mt, nt, bz;
  if constexpr (MODE == 3 || MODE == 4) {
    constexpr int PER = (MODE == 3) ? 81 : 36;
    constexpr int NTW = (MODE == 3) ? 9 : 4;
    int flat = blockIdx.x;
    int xcd = flat & 7, s = flat >> 3;
    bz = xcd + 8 * (s / PER);
    int tile = s % PER;
    mt = tile / NTW;
    nt = tile % NTW;
  } else if constexpr (MODE == 1) {
    int flat = blockIdx.x;               // 2048 blocks
    int xcd = flat & 7, s = flat >> 3;   // s: 0..255
    bz = s >> 7;                         // 0 = Q-pool, 1 = K-pool
    int rem = s & 127;
    mt = xcd * 32 + (rem >> 2);          // contiguous 32-mt slice per XCD
    nt = rem & 3;
  } else if constexpr (MODE == 2) {
    int flat = blockIdx.x;               // 1024 blocks
    int xcd = flat & 7, s = flat >> 3;   // s: 0..127
    bz = 0;
    mt = xcd * 32 + (s >> 2);
    nt = s & 3;
  } else {
    mt = blockIdx.y; nt = blockIdx.x; bz = blockIdx.z;
  }
  const int gbz = g.bz0 + bz;

  const u16* Ap = g.A;
  const u16* Bp = g.B;
  if constexpr (MODE == 1) {
    if (bz == 1) { Ap = g.A2; Bp = g.B2; }
  }

  int a_row[4], b_row[4], kx[4];
#pragma unroll
  for (int c = 0; c < 4; ++c) {
    int idx = c * 256 + tid;
    int row = idx >> 3;                       // 0..127
    kx[c] = ((idx & 7) ^ (row & 7)) * 8;      // swizzled k-chunk offset (elems)
    {
      int r = mt * 128 + row;
      int off;
      if constexpr (MODE == 0) { r = r < 4099 ? r : 4099; off = r * 512; }
      else if constexpr (MODE == 1 || MODE == 2) { off = ((r >> 10) * 1025 + 1 + (r & 1023)) * 512; }
      else if constexpr (MODE == 3) { r = r < 1024 ? r : 1024; off = gbz * (1025 * 512) + r * 512; }
      else if constexpr (MODE == 4) { r = r < 1024 ? r : 1024; off = bz * (1025 * 1088) + r * 1088; }
      else { r = r < 4099 ? r : 4099; off = r * 4096; }
      a_row[c] = off;
    }
    {
      int r = nt * 128 + row;
      int off;
      if constexpr (MODE == 3) { r = r < 1024 ? r : 1024; off = gbz * (1025 * 512) + r * 512; }
      else if constexpr (MODE == 4) { off = gbz * (512 * 1088) + r * 1088; }
      else if constexpr (MODE == 5) { off = r * 4096; }
      else { off = r * 512; }
      b_row[c] = off;
    }
  }

  // Accumulators: modes 0/1 initialize with the (per-column) bias -- MFMA
  // accumulates on top; bias regs are dead before the K-loop starts.
  floatx4 acc[4][4];
  {
    float binit[4] = {0.f, 0.f, 0.f, 0.f};
    if constexpr (MODE == 0) {
      int sec = nt >> 5;
      const float* bs = (sec == 0) ? g.c0 : (sec == 1) ? g.c1 : g.c2;
#pragma unroll
      for (int j = 0; j < 4; ++j) binit[j] = bs[(nt & 31) * 128 + wc * 64 + j * 16 + ccol];
    }
    if constexpr (MODE == 1) {
      const float* bs = bz ? g.c1 : g.c0;
#pragma unroll
      for (int j = 0; j < 4; ++j) binit[j] = bs[nt * 128 + wc * 64 + j * 16 + ccol];
    }
    if constexpr (MODE == 2) {
#pragma unroll
      for (int j = 0; j < 4; ++j) binit[j] = g.c0[nt * 128 + wc * 64 + j * 16 + ccol];
    }
#pragma unroll
    for (int i = 0; i < 4; ++i)
#pragma unroll
      for (int j = 0; j < 4; ++j)
#pragma unroll
        for (int rr = 0; rr < 4; ++rr) acc[i][j][rr] = binit[j];
  }

  const int kbase = (MODE == 5) ? bz * 1024 : 0;
  const int l15 = lane & 15;
  const int lq = lane >> 4;
  const int l7 = lane & 7;

  for (int kt = 0; kt < KITER; ++kt) {
    const int k0 = kbase + kt * 64;
#pragma unroll
    for (int c = 0; c < 4; ++c)
      gld_lds16(Ap + a_row[c] + k0 + kx[c], (char*)As + (c * 256 + wv * 64) * 16);
#pragma unroll
    for (int c = 0; c < 4; ++c)
      gld_lds16(Bp + b_row[c] + k0 + kx[c], (char*)Bs + (c * 256 + wv * 64) * 16);
    __syncthreads();
#pragma unroll
    for (int ks = 0; ks < 2; ++ks) {
      const int ch = ((ks * 4 + lq) ^ l7) * 8;
      short8 af[4], bf[4];
#pragma unroll
      for (int i = 0; i < 4; ++i)
        af[i] = *(const short8*)(As + (wr * 64 + i * 16 + l15) * 64 + ch);
#pragma unroll
      for (int j = 0; j < 4; ++j)
        bf[j] = *(const short8*)(Bs + (wc * 64 + j * 16 + l15) * 64 + ch);
#pragma unroll
      for (int i = 0; i < 4; ++i)
#pragma unroll
        for (int j = 0; j < 4; ++j)
          acc[i][j] = __builtin_amdgcn_mfma_f32_16x16x32_bf16(af[i], bf[j], acc[i][j], 0, 0, 0);
    }
    __syncthreads();
  }

  // ---- Epilogue ---- (C/D frag: col = lane&15, row = (lane>>4)*4 + reg)
  if constexpr (LDSEP) {
#pragma unroll
    for (int i = 0; i < 4; ++i)
#pragma unroll
      for (int j = 0; j < 4; ++j)
#pragma unroll
        for (int rr = 0; rr < 4; ++rr) {
          int lr = wr * 64 + i * 16 + rgrp * 4 + rr;
          int lc = wc * 64 + j * 16 + ccol;
          float v = acc[i][j][rr];
          if constexpr (MODE == 3) v *= 0.04419417382415922f;
          smem[lr * 128 + (lc ^ (rgrp << 4))] = f2bf(v);
        }
    __syncthreads();
#pragma unroll
    for (int q = 0; q < 8; ++q) {
      int cid = q * 256 + tid;
      int r = cid >> 4;                 // 0..127
      int c = cid & 15;                 // chunk
      int pc = c ^ ((((unsigned)r >> 2) & 3) << 1);
      short8 val = *(const short8*)(smem + r * 128 + pc * 8);
      int grow = mt * 128 + r;
      if constexpr (MODE == 0) {
        if (grow < 4100) {
          int sec = nt >> 5;                     // block-uniform
          int col = (nt & 31) * 128 + c * 8;     // 0..4095
          u16* ob = (sec == 0) ? g.o0 : (sec == 1) ? g.o1 : g.o2;
          int b = grow / 1025, l = grow - b * 1025;
          int n = col >> 9, ch2 = col & 511;
          *(short8*)(ob + ((long)(b * 8 + n) * 1025 + l) * 512 + ch2) = val;
        }
      } else if constexpr (MODE == 1) {
        int bn = grow >> 10, sp = grow & 1023;
        int gcol = nt * 128 + c * 8;             // 0..511
        short8 outv = val;
        if (bz == 0) {
          const float* ep = g.emb + sp * 512 + gcol;
          float4 e0 = *(const float4*)ep;
          float4 e1 = *(const float4*)(ep + 4);
          float ee[8] = {e0.x, e0.y, e0.z, e0.w, e1.x, e1.y, e1.z, e1.w};
#pragma unroll
          for (int e = 0; e < 8; ++e) outv[e] = (short)f2bf(bf2f((u16)val[e]) + ee[e]);
        }
        u16* dst = (bz == 0) ? g.o0 : g.o1;
        *(short8*)(dst + ((long)bn * 1025 + 1 + sp) * 512 + gcol) = outv;
      } else if constexpr (MODE == 3) {
        if (grow <= 1024) {
          int gcol0 = nt * 128 + c * 8;
          u16* dst = g.o0 + ((long)bz * 1025 + grow) * 1088 + gcol0;
          if (gcol0 + 7 <= 1024) *(short8*)dst = val;
          else if (gcol0 <= 1024) dst[0] = (u16)val[0];
        }
      } else {  // MODE 4
        if (grow <= 1024) {
          int gcol0 = nt * 128 + c * 8;          // 0..511
          short8 outv = val;
          if (grow >= 1) {
            short8 rs = *(const short8*)(g.resid + ((long)gbz * 1025 + grow) * 512 + gcol0);
#pragma unroll
            for (int e = 0; e < 8; ++e)
              outv[e] = (short)f2bf(bf2f((u16)val[e]) + bf2f((u16)rs[e]));
          }
          int b = gbz >> 3, n = gbz & 7;
          *(short8*)(g.o0 + (((long)b * 1025 + grow) * 8 + n) * 512 + gcol0) = outv;
        }
      }
    }
  } else {
    // Scalar epilogue for modes 2 (transposed PVt pool; bias already in acc)
    // and 5 (f32 partials).
#pragma unroll
    for (int i = 0; i < 4; ++i) {
#pragma unroll
      for (int j = 0; j < 4; ++j) {
        const int gcol = nt * 128 + wc * 64 + j * 16 + ccol;
#pragma unroll
        for (int rr = 0; rr < 4; ++rr) {
          const int grow = mt * 128 + wr * 64 + i * 16 + rgrp * 4 + rr;
          float v = acc[i][j][rr];
          if constexpr (MODE == 2) {
            int bn = grow >> 10, sp = grow & 1023;
            g.o0[((long)bn * 512 + gcol) * 1088 + 1 + sp] = f2bf(v);
          } else {
            if (grow < 4100)
              g.of[((long)bz * 4100 + grow) * 512 + gcol] = v;   // partial
          }
        }
      }
    }
  }
}

// ---------------------------------------------------------------------------
extern "C" void kernel_launch(void* const* d_in, const int* in_sizes, int n_in,
                              void* d_out, int out_size, void* d_ws, size_t ws_size,
                              hipStream_t stream) {
  const float* x   = (const float*)d_in[0];
  const float* Wq  = (const float*)d_in[1];
  const float* bq  = (const float*)d_in[2];
  const float* Wk  = (const float*)d_in[3];
  const float* bk  = (const float*)d_in[4];
  const float* Wv  = (const float*)d_in[5];
  const float* bv  = (const float*)d_in[6];
  const float* Wpq = (const float*)d_in[7];
  const float* bpq = (const float*)d_in[8];
  const float* Wpk = (const float*)d_in[9];
  const float* bpk = (const float*)d_in[10];
  const float* Wpv = (const float*)d_in[11];
  const float* bpv = (const float*)d_in[12];
  const float* Wd  = (const float*)d_in[13];
  const float* bd  = (const float*)d_in[14];
  float* out = (float*)d_out;

  char* ws = (char*)d_ws;
  size_t off = 0;
  auto alloc = [&](size_t bytes) {
    char* p = ws + off;
    off += (bytes + 255) & ~(size_t)255;
    return p;
  };
  // Persistent through attention:
  u16* Wpqb = (u16*)alloc(512ull * 512 * 2);
  u16* Wpkb = (u16*)alloc(512ull * 512 * 2);
  u16* Wpvb = (u16*)alloc(512ull * 512 * 2);
  u16* Wdb  = (u16*)alloc(4096ull * 512 * 2);
  u16* Q    = (u16*)alloc(32ull * 1025 * 512 * 2);
  u16* PQ   = (u16*)alloc(32ull * 1025 * 512 * 2);   // later: f32 partials
  u16* PK   = (u16*)alloc(32ull * 1025 * 512 * 2);   // later: stk (nchunk=1)
  u16* PVt  = (u16*)alloc(32ull * 512 * 1088 * 2);
  // Dead-by-attention group (S aliases from here):
  size_t s_off = off;
  u16* K    = (u16*)alloc(32ull * 1025 * 512 * 2);
  u16* V    = (u16*)alloc(32ull * 1025 * 512 * 2);
  u16* xb   = (u16*)alloc(4100ull * 512 * 2);
  u16* Wqb  = (u16*)alloc(4096ull * 512 * 2);   // Wqb|Wkb|Wvb contiguous
  u16* Wkb  = (u16*)alloc(4096ull * 512 * 2);
  u16* Wvb  = (u16*)alloc(4096ull * 512 * 2);
  float* embp = (float*)alloc(1024ull * 512 * 4);
  size_t fixed_need = off;
  u16* S = (u16*)(ws + s_off);
  float* part = (float*)PQ;   // PQ dead before partials written
  (void)in_sizes; (void)n_in; (void)out_size;

  const size_t sbytes = 1025ull * 1088 * 2;
  size_t need1 = s_off + 32ull * sbytes;
  size_t need2 = s_off + 16ull * sbytes;
  size_t stk4_off = s_off + ((8ull * sbytes + 255) & ~(size_t)255);
  size_t need4 = stk4_off + 4100ull * 4096 * 2;
  int nchunk;
  u16* stk;
  if (ws_size >= need1)      { nchunk = 1; stk = PK; }   // PK dead after mode 3
  else if (ws_size >= need2 && ws_size >= fixed_need) { nchunk = 2; stk = PK; }
  else if (ws_size >= need4 && ws_size >= fixed_need) {
    nchunk = 4; stk = (u16*)(ws + stk4_off);
  } else return;  // clean fail instead of GPU fault
  if (nchunk == 2) {
    size_t stk2_off = s_off + ((16ull * sbytes + 255) & ~(size_t)255);
    if (ws_size >= stk2_off + 4100ull * 4096 * 2) stk = (u16*)(ws + stk2_off);
    else {
      nchunk = 4;
      if (ws_size >= need4) stk = (u16*)(ws + stk4_off);
      else return;
    }
  }
  int hpc = 32 / nchunk;

  // 1) dtype conversions
  CvtArgs ca;
  ca.src[0] = x;   ca.dst[0] = xb;   ca.n4[0] = 4100 * 512 / 4;
  ca.src[1] = Wq;  ca.dst[1] = Wqb;  ca.n4[1] = 4096 * 512 / 4;
  ca.src[2] = Wk;  ca.dst[2] = Wkb;  ca.n4[2] = 4096 * 512 / 4;
  ca.src[3] = Wv;  ca.dst[3] = Wvb;  ca.n4[3] = 4096 * 512 / 4;
  ca.src[4] = Wpq; ca.dst[4] = Wpqb; ca.n4[4] = 512 * 512 / 4;
  ca.src[5] = Wpk; ca.dst[5] = Wpkb; ca.n4[5] = 512 * 512 / 4;
  ca.src[6] = Wpv; ca.dst[6] = Wpvb; ca.n4[6] = 512 * 512 / 4;
  ca.src[7] = Wd;  ca.dst[7] = Wdb;  ca.n4[7] = 512 * 4096 / 4;
  int total4 = 0;
  for (int s = 0; s < 8; ++s) total4 += ca.n4[s];
  cvt_all<<<(total4 + 255) / 256, 256, 0, stream>>>(ca, total4);

  // 2) positional embedding
  emb_kernel<<<(1024 * 512) / 256, 256, 0, stream>>>(embp);

  // 3) merged Q+K+V projection (B = [Wq|Wk|Wv], N=12288), one dispatch
  {
    GP g = {};
    g.A = xb; g.B = Wqb;
    g.c0 = bq; g.c1 = bk; g.c2 = bv;
    g.o0 = Q; g.o1 = K; g.o2 = V;
    gemm_bt<0><<<dim3(96, 33, 1), 256, 0, stream>>>(g);
  }

  // 4) cls passthrough (one kernel)
  cls_all<<<(32 * 512) / 256, 256, 0, stream>>>(Q, K, V, PQ, PK, PVt);

  // 5) pools: Q(+emb) and K in one lean mode-1 dispatch; V pool separate
  {
    GP g = {};
    g.A = Q; g.A2 = K; g.B = Wpqb; g.B2 = Wpkb;
    g.c0 = bpq; g.c1 = bpk; g.emb = embp;
    g.o0 = PQ; g.o1 = PK;
    gemm_bt<1><<<dim3(2048, 1, 1), 256, 0, stream>>>(g);
  }
  {
    GP g = {};
    g.A = V; g.B = Wpvb; g.c0 = bpv; g.o0 = PVt;
    gemm_bt<2><<<dim3(1024, 1, 1), 256, 0, stream>>>(g);
  }
  // K, V, xb, Wqkv, embp now dead -> S aliases them.

  // 6) attention: logits -> softmax -> O (+Q resid). All XCD head-grouped.
  for (int c = 0; c < nchunk; ++c) {
    GP g3 = {}; g3.A = PQ; g3.B = PK; g3.o0 = S; g3.bz0 = c * hpc;
    gemm_bt<3><<<dim3(81 * hpc, 1, 1), 256, 0, stream>>>(g3);
    softmax_rows<<<257 * hpc, 256, 0, stream>>>(S);
    GP g4 = {}; g4.A = S; g4.B = PVt; g4.resid = Q; g4.o0 = stk; g4.bz0 = c * hpc;
    gemm_bt<4><<<dim3(36 * hpc, 1, 1), 256, 0, stream>>>(g4);
  }
  // PQ dead -> f32 partials alias it.

  // 7) final projection, split-K x4 -> partials, then reduce (+bias)
  {
    GP g = {}; g.A = stk; g.B = Wdb; g.of = part;
    gemm_bt<5><<<dim3(4, 33, 4), 256, 0, stream>>>(g);
  }
  reduce4<<<(4100 * 512 / 4 + 255) / 256, 256, 0, stream>>>(part, bd, out);
}